// Round 5
// baseline (917.756 us; speedup 1.0000x reference)
//
#include <hip/hip_runtime.h>
#include <math.h>

#define CC 64
#define KK 20
#define DCH 32
#define LOG2E 1.4426950408889634f
#define LN2   0.6931471805599453f
#define LN2PI 1.8378770664093453f
#define BIGN  -1.0e9f

#if __has_builtin(__builtin_amdgcn_exp2f)
#define EXP2(x) __builtin_amdgcn_exp2f(x)
#else
#define EXP2(x) exp2f(x)
#endif
#if __has_builtin(__builtin_amdgcn_logf)
#define LOG2(x) __builtin_amdgcn_logf(x)
#else
#define LOG2(x) log2f(x)
#endif

__device__ __forceinline__ float rlane(float v, int l) {
  return __int_as_float(__builtin_amdgcn_readlane(__float_as_int(v), l));
}

template <int Ctrl, int OldBits>
__device__ __forceinline__ float dpp_mov(float x) {
  return __int_as_float(__builtin_amdgcn_update_dpp(
      OldBits, __float_as_int(x), Ctrl, 0xf, 0xf, false));
}

__device__ __forceinline__ float wave_max64(float x) {
  constexpr int NI = (int)0xff800000;  // -inf
  x = fmaxf(x, dpp_mov<0x111, NI>(x));
  x = fmaxf(x, dpp_mov<0x112, NI>(x));
  x = fmaxf(x, dpp_mov<0x114, NI>(x));
  x = fmaxf(x, dpp_mov<0x118, NI>(x));
  x = fmaxf(x, dpp_mov<0x142, NI>(x));
  x = fmaxf(x, dpp_mov<0x143, NI>(x));
  return __int_as_float(__builtin_amdgcn_readlane(__float_as_int(x), 63));
}

// two independent wave-max reductions, chains interleaved for ILP
__device__ __forceinline__ void wave_max64_pair(float& x, float& y,
                                                float& ox, float& oy) {
  constexpr int NI = (int)0xff800000;
  float a = x, b = y;
  a = fmaxf(a, dpp_mov<0x111, NI>(a)); b = fmaxf(b, dpp_mov<0x111, NI>(b));
  a = fmaxf(a, dpp_mov<0x112, NI>(a)); b = fmaxf(b, dpp_mov<0x112, NI>(b));
  a = fmaxf(a, dpp_mov<0x114, NI>(a)); b = fmaxf(b, dpp_mov<0x114, NI>(b));
  a = fmaxf(a, dpp_mov<0x118, NI>(a)); b = fmaxf(b, dpp_mov<0x118, NI>(b));
  a = fmaxf(a, dpp_mov<0x142, NI>(a)); b = fmaxf(b, dpp_mov<0x142, NI>(b));
  a = fmaxf(a, dpp_mov<0x143, NI>(a)); b = fmaxf(b, dpp_mov<0x143, NI>(b));
  ox = __int_as_float(__builtin_amdgcn_readlane(__float_as_int(a), 63));
  oy = __int_as_float(__builtin_amdgcn_readlane(__float_as_int(b), 63));
}

__device__ __forceinline__ float wave_sum64(float x) {
  x += dpp_mov<0x111, 0>(x);
  x += dpp_mov<0x112, 0>(x);
  x += dpp_mov<0x114, 0>(x);
  x += dpp_mov<0x118, 0>(x);
  x += dpp_mov<0x142, 0>(x);
  x += dpp_mov<0x143, 0>(x);
  return __int_as_float(__builtin_amdgcn_readlane(__float_as_int(x), 63));
}

// ---------------------------------------------------------------------------
// Setup (unchanged)
// ---------------------------------------------------------------------------
__global__ void setup_kernel(const float* __restrict__ means,
                             const float* __restrict__ cov,
                             const float* __restrict__ tl,
                             const float* __restrict__ il,
                             const float* __restrict__ plr,
                             float* __restrict__ wmat,
                             float* __restrict__ invvar,
                             float* __restrict__ sinv,
                             float* __restrict__ q2,
                             float* __restrict__ P_T,
                             float* __restrict__ init2,
                             float* __restrict__ len2,
                             int D) {
  __shared__ float red[256];
  int tid = threadIdx.x;
  for (int d = tid; d < D; d += 256) {
    float v = 1.0f / cov[(size_t)d * D + d];
    invvar[d] = v;
    sinv[d] = sqrtf(v);
  }
  float lp_ = 0.f;
  for (int d = tid; d < D; d += 256) lp_ += logf(cov[(size_t)d * D + d]);
  red[tid] = lp_;
  __syncthreads();
  for (int s = 128; s > 0; s >>= 1) {
    if (tid < s) red[tid] += red[tid + s];
    __syncthreads();
  }
  float logdet = red[0];
  __syncthreads();
  {
    int c = tid & 63, q = tid >> 6;
    int dq = D / 4;
    float m2p = 0.f;
    for (int d = q * dq; d < (q + 1) * dq; ++d) {
      float mu = means[c * D + d];
      m2p = fmaf(mu * mu, invvar[d], m2p);
    }
    red[tid] = m2p;
  }
  __syncthreads();
  for (int i = tid; i < CC * D; i += 256) wmat[i] = means[i] * sinv[i % D];
  if (tid < CC) {
    int c = tid;
    float m2 = red[c] + red[c + 64] + red[c + 128] + red[c + 192];
    q2[c] = -0.5f * LOG2E * (m2 + logdet + (float)D * LN2PI);
    int j = c;
    float mx = -1e30f;
    for (int i2 = 0; i2 < CC; ++i2) {
      float v = (i2 == j) ? BIGN : tl[i2 * CC + j];
      mx = fmaxf(mx, v);
    }
    float s = 0.f;
    for (int i2 = 0; i2 < CC; ++i2) {
      float v = (i2 == j) ? BIGN : tl[i2 * CC + j];
      s += expf(v - mx);
    }
    float inv = 1.f / s;
    for (int i2 = 0; i2 < CC; ++i2) {
      float v = (i2 == j) ? BIGN : tl[i2 * CC + j];
      P_T[j * CC + i2] = expf(v - mx) * inv;
    }
    float mi = -1e30f;
    for (int i2 = 0; i2 < CC; ++i2) mi = fmaxf(mi, il[i2]);
    float si = 0.f;
    for (int i2 = 0; i2 < CC; ++i2) si += expf(il[i2] - mi);
    init2[c] = LOG2E * (il[c] - (mi + logf(si)));
  }
  for (int i = tid; i < KK * CC; i += 256) {
    int k = i / CC, c = i % CC;
    float lr = plr[c];
    float lp = (float)(k + 1) * lr - expf(lr) - lgammaf((float)(k + 2));
    len2[i] = LOG2E * lp;
  }
}

// ---------------------------------------------------------------------------
// Emission (unchanged)
// ---------------------------------------------------------------------------
__global__ __launch_bounds__(256) void emission_kernel(
    const float* __restrict__ feat,
    const float* __restrict__ wmat,
    const float* __restrict__ sinv,
    const float* __restrict__ q2,
    float* __restrict__ emhat,
    float* __restrict__ kmax,
    int D) {
  __shared__ __align__(16) float xsT[DCH][68];
  __shared__ __align__(16) float wsT[DCH][68];
  __shared__ float q2s[CC];
  __shared__ float x2row[64];
  __shared__ float rmx[64][17];
  __shared__ float kapsh[64];
  int tid = threadIdx.x;
  size_t row0 = (size_t)blockIdx.x * 64;
  if (tid < CC) q2s[tid] = q2[tid];
  int lr_ = tid >> 2;
  int lq  = tid & 3;
  int lj  = lq * 8;
  int tx = tid & 15, ty = tid >> 4;
  int r0 = ty * 4, c0 = tx * 4;

  const float* fx = feat + (row0 + (size_t)lr_) * D + lj;
  const float* fw = wmat + (size_t)lr_ * D + lj;
  const float* fs = sinv + lj;

  float4 xa = *(const float4*)(fx);
  float4 xb = *(const float4*)(fx + 4);
  float4 wa = *(const float4*)(fw);
  float4 wb = *(const float4*)(fw + 4);
  float4 sa = *(const float4*)(fs);
  float4 sb = *(const float4*)(fs + 4);

  float acc[4][4] = {{0.f}};
  float x2p = 0.f;

  for (int d0 = 0; d0 < D; d0 += DCH) {
    __syncthreads();
    {
      float xs0 = xa.x * sa.x, xs1 = xa.y * sa.y, xs2 = xa.z * sa.z, xs3 = xa.w * sa.w;
      float xs4 = xb.x * sb.x, xs5 = xb.y * sb.y, xs6 = xb.z * sb.z, xs7 = xb.w * sb.w;
      xsT[lj + 0][lr_] = xs0; xsT[lj + 1][lr_] = xs1;
      xsT[lj + 2][lr_] = xs2; xsT[lj + 3][lr_] = xs3;
      xsT[lj + 4][lr_] = xs4; xsT[lj + 5][lr_] = xs5;
      xsT[lj + 6][lr_] = xs6; xsT[lj + 7][lr_] = xs7;
      wsT[lj + 0][lr_] = wa.x; wsT[lj + 1][lr_] = wa.y;
      wsT[lj + 2][lr_] = wa.z; wsT[lj + 3][lr_] = wa.w;
      wsT[lj + 4][lr_] = wb.x; wsT[lj + 5][lr_] = wb.y;
      wsT[lj + 6][lr_] = wb.z; wsT[lj + 7][lr_] = wb.w;
      x2p = fmaf(xs0, xs0, x2p); x2p = fmaf(xs1, xs1, x2p);
      x2p = fmaf(xs2, xs2, x2p); x2p = fmaf(xs3, xs3, x2p);
      x2p = fmaf(xs4, xs4, x2p); x2p = fmaf(xs5, xs5, x2p);
      x2p = fmaf(xs6, xs6, x2p); x2p = fmaf(xs7, xs7, x2p);
    }
    __syncthreads();
    if (d0 + DCH < D) {
      fx += DCH; fw += DCH; fs += DCH;
      xa = *(const float4*)(fx);
      xb = *(const float4*)(fx + 4);
      wa = *(const float4*)(fw);
      wb = *(const float4*)(fw + 4);
      sa = *(const float4*)(fs);
      sb = *(const float4*)(fs + 4);
    }
    #pragma unroll
    for (int j = 0; j < DCH; ++j) {
      float4 xv = *(const float4*)&xsT[j][r0];
      float4 wv = *(const float4*)&wsT[j][c0];
      acc[0][0] = fmaf(xv.x, wv.x, acc[0][0]);
      acc[0][1] = fmaf(xv.x, wv.y, acc[0][1]);
      acc[0][2] = fmaf(xv.x, wv.z, acc[0][2]);
      acc[0][3] = fmaf(xv.x, wv.w, acc[0][3]);
      acc[1][0] = fmaf(xv.y, wv.x, acc[1][0]);
      acc[1][1] = fmaf(xv.y, wv.y, acc[1][1]);
      acc[1][2] = fmaf(xv.y, wv.z, acc[1][2]);
      acc[1][3] = fmaf(xv.y, wv.w, acc[1][3]);
      acc[2][0] = fmaf(xv.z, wv.x, acc[2][0]);
      acc[2][1] = fmaf(xv.z, wv.y, acc[2][1]);
      acc[2][2] = fmaf(xv.z, wv.z, acc[2][2]);
      acc[2][3] = fmaf(xv.z, wv.w, acc[2][3]);
      acc[3][0] = fmaf(xv.w, wv.x, acc[3][0]);
      acc[3][1] = fmaf(xv.w, wv.y, acc[3][1]);
      acc[3][2] = fmaf(xv.w, wv.z, acc[3][2]);
      acc[3][3] = fmaf(xv.w, wv.w, acc[3][3]);
    }
  }

  x2p += dpp_mov<0xB1, 0>(x2p);
  x2p += dpp_mov<0x4E, 0>(x2p);
  if (lq == 0) x2row[lr_] = x2p;
  __syncthreads();

  float e[4][4];
  #pragma unroll
  for (int i = 0; i < 4; ++i) {
    float h = 0.5f * x2row[r0 + i];
    #pragma unroll
    for (int k2 = 0; k2 < 4; ++k2)
      e[i][k2] = LOG2E * (acc[i][k2] - h) + q2s[c0 + k2];
  }
  #pragma unroll
  for (int i = 0; i < 4; ++i)
    rmx[r0 + i][tx] = fmaxf(fmaxf(e[i][0], e[i][1]), fmaxf(e[i][2], e[i][3]));
  __syncthreads();
  if (tid < 64) {
    float m = rmx[tid][0];
    #pragma unroll
    for (int j = 1; j < 16; ++j) m = fmaxf(m, rmx[tid][j]);
    kapsh[tid] = m;
    kmax[row0 + tid] = m;
  }
  __syncthreads();
  #pragma unroll
  for (int i = 0; i < 4; ++i) {
    float kp = kapsh[r0 + i];
    size_t row = row0 + r0 + i;
    float4 o;
    o.x = EXP2(e[i][0] - kp); o.y = EXP2(e[i][1] - kp);
    o.z = EXP2(e[i][2] - kp); o.w = EXP2(e[i][3] - kp);
    *(float4*)&emhat[row * CC + c0] = o;
  }
}

// ---------------------------------------------------------------------------
// Recursion v4: back to the proven single-wave structure (R0, 388us), but
// TWO independent batch chains interleaved in one wave. P[64] and W[21] are
// shared; per-batch state (~30 VGPR) duplicated. Every stage is manually
// paired so the two chains fill each other's readlane-SGPR-hazard and DPP
// dependency stalls. No LDS, no barriers. Grid = B/2 blocks x 64 threads.
// ---------------------------------------------------------------------------
__global__ __launch_bounds__(64, 1) void recur_kernel(
    const float* __restrict__ emhat,
    const float* __restrict__ kmax,
    const float* __restrict__ P_T,
    const float* __restrict__ init2,
    const float* __restrict__ len2,
    const int* __restrict__ lengths,
    float* __restrict__ out,
    int N, int B) {
  int b0 = blockIdx.x * 2;
  int b1 = (b0 + 1 < B) ? (b0 + 1) : b0;   // duplicate last if B odd
  int c = threadIdx.x;

  float P[CC];
  #pragma unroll
  for (int j = 0; j < CC; ++j) P[j] = P_T[j * CC + c];
  float W[KK + 1];
  #pragma unroll
  for (int k = 1; k <= KK; ++k) W[k] = EXP2(len2[(k - 1) * CC + c]);
  float W1 = W[1];

  const float* eh0 = emhat + (size_t)b0 * N * CC;
  const float* eh1 = emhat + (size_t)b1 * N * CC;
  const float* km0 = kmax + (size_t)b0 * N;
  const float* km1 = kmax + (size_t)b1 * N;
  int len0 = lengths[b0];
  int len1 = lengths[b1];

  float sk0 = 0.f, sk1 = 0.f;
  for (int r = c; r < len0; r += 64) sk0 += km0[r];
  for (int r = c; r < len1; r += 64) sk1 += km1[r];
  float Skap0 = wave_sum64(sk0);
  float Skap1 = wave_sum64(sk1);

  float vini = EXP2(init2[c]);
  float v0 = vini, v1 = vini;
  float rho0 = eh0[c], rho1 = eh1[c];
  int i1 = (1 <= N - 1) ? 1 : N - 1;
  int i2_ = (2 <= N - 1) ? 2 : N - 1;
  int i3 = (3 <= N - 1) ? 3 : N - 1;
  int i4 = (4 <= N - 1) ? 4 : N - 1;
  float qa0 = eh0[(size_t)i1 * CC + c], qa1 = eh1[(size_t)i1 * CC + c];
  float qb0 = eh0[(size_t)i2_ * CC + c], qb1 = eh1[(size_t)i2_ * CC + c];
  float qc0 = eh0[(size_t)i3 * CC + c], qc1 = eh1[(size_t)i3 * CC + c];
  float qd0 = eh0[(size_t)i4 * CC + c], qd1 = eh1[(size_t)i4 * CC + c];
  float Ef0 = 0.f, Ef1 = 0.f;
  float A0r[KK], A1r[KK];
  #pragma unroll
  for (int i = 0; i < KK; ++i) { A0r[i] = 0.f; A1r[i] = 0.f; }
  float rest0 = 0.f, rest1 = 0.f;

  auto body = [&](int t, float& qx0, float& qx1) {
    // ---- serial chain heads (independent pair) ----
    float H0 = v0 * rho0;
    float H1 = v1 * rho1;
    float a0 = fmaf(H0, W1, rest0);
    float a1 = fmaf(H1, W1, rest1);

    if (t == len0) {
      float s_ = wave_sum64(a0);
      if (c == 0) out[b0] = LN2 * (Skap0 + Ef0 + LOG2(s_));
    }
    if (t == len1 && b1 != b0) {
      float s_ = wave_sum64(a1);
      if (c == 0) out[b1] = LN2 * (Skap1 + Ef1 + LOG2(s_));
    }

    // ---- matvec pair, interleaved readlane streams ----
    float m00 = 0.f, m01 = 0.f, m02 = 0.f, m03 = 0.f;
    float m10 = 0.f, m11 = 0.f, m12 = 0.f, m13 = 0.f;
    #pragma unroll
    for (int j = 0; j < CC; j += 4) {
      m00 = fmaf(P[j],     rlane(a0, j),     m00);
      m10 = fmaf(P[j],     rlane(a1, j),     m10);
      m01 = fmaf(P[j + 1], rlane(a0, j + 1), m01);
      m11 = fmaf(P[j + 1], rlane(a1, j + 1), m11);
      m02 = fmaf(P[j + 2], rlane(a0, j + 2), m02);
      m12 = fmaf(P[j + 2], rlane(a1, j + 2), m12);
      m03 = fmaf(P[j + 3], rlane(a0, j + 3), m03);
      m13 = fmaf(P[j + 3], rlane(a1, j + 3), m13);
    }
    float vn0 = (m00 + m01) + (m02 + m03);
    float vn1 = (m10 + m11) + (m12 + m13);

    // ---- S2 pair from OLD rings ----
    float u00 = H0 * W[2], u01 = 0.f, u02 = 0.f, u03 = 0.f;
    float u10 = H1 * W[2], u11 = 0.f, u12 = 0.f, u13 = 0.f;
    #pragma unroll
    for (int i = 1; i + 3 <= 16; i += 4) {
      u00 = fmaf(A0r[i],     W[i + 2], u00);
      u10 = fmaf(A1r[i],     W[i + 2], u10);
      u01 = fmaf(A0r[i + 1], W[i + 3], u01);
      u11 = fmaf(A1r[i + 1], W[i + 3], u11);
      u02 = fmaf(A0r[i + 2], W[i + 4], u02);
      u12 = fmaf(A1r[i + 2], W[i + 4], u12);
      u03 = fmaf(A0r[i + 3], W[i + 5], u03);
      u13 = fmaf(A1r[i + 3], W[i + 5], u13);
    }
    u01 = fmaf(A0r[17], W[19], u01);
    u11 = fmaf(A1r[17], W[19], u11);
    u02 = fmaf(A0r[18], W[20], u02);
    u12 = fmaf(A1r[18], W[20], u12);
    float S20 = (u00 + u01) + (u02 + u03);
    float S21 = (u10 + u11) + (u12 + u13);

    // ---- prefetch rotation pair ----
    float rh0 = qx0, rh1 = qx1;
    int rown = (t + 4 <= N - 1) ? (t + 4) : (N - 1);
    qx0 = eh0[(size_t)rown * CC + c];
    qx1 = eh1[(size_t)rown * CC + c];

    // ---- renorm pair (uses OLD v; interleaved DPP chains) ----
    float vm0, vm1;
    wave_max64_pair(v0, v1, vm0, vm1);
    vm0 = fminf(fmaxf(vm0, 1e-20f), 1e20f);
    vm1 = fminf(fmaxf(vm1, 1e-20f), 1e20f);
    int e0 = (__float_as_int(vm0) >> 23) & 255;
    int e1 = (__float_as_int(vm1) >> 23) & 255;
    float sc0 = __int_as_float((254 - e0) << 23);
    float sc1 = __int_as_float((254 - e1) << 23);
    Ef0 += (float)(e0 - 127);
    Ef1 += (float)(e1 - 127);
    float rn0 = rh0 * sc0;
    float rn1 = rh1 * sc1;
    rest0 = rn0 * S20;
    rest1 = rn1 * S21;

    // ---- ring shift pair ----
    #pragma unroll
    for (int i = KK - 1; i >= 2; --i) {
      A0r[i] = A0r[i - 1] * rn0;
      A1r[i] = A1r[i - 1] * rn1;
    }
    A0r[1] = H0 * rn0;
    A1r[1] = H1 * rn1;

    v0 = vn0; v1 = vn1;
    rho0 = rn0; rho1 = rn1;
  };

  int t = 1;
  for (; t + 3 <= N; t += 4) {
    body(t,     qa0, qa1);
    body(t + 1, qb0, qb1);
    body(t + 2, qc0, qc1);
    body(t + 3, qd0, qd1);
  }
  for (; t <= N; ++t) {
    int s = t & 3;
    if (s == 1)      body(t, qa0, qa1);
    else if (s == 2) body(t, qb0, qb1);
    else if (s == 3) body(t, qc0, qc1);
    else             body(t, qd0, qd1);
  }
}

extern "C" void kernel_launch(void* const* d_in, const int* in_sizes, int n_in,
                              void* d_out, int out_size, void* d_ws, size_t ws_size,
                              hipStream_t stream) {
  const float* feat   = (const float*)d_in[0];
  const int*   lens   = (const int*)d_in[1];
  const float* means  = (const float*)d_in[2];
  const float* cov    = (const float*)d_in[3];
  const float* tl     = (const float*)d_in[4];
  const float* il     = (const float*)d_in[5];
  const float* plr    = (const float*)d_in[6];
  int B = in_sizes[1];
  int D = in_sizes[2] / CC;
  int N = in_sizes[0] / (B * D);

  float* ws = (float*)d_ws;
  size_t off = 0;
  float* wmat   = ws + off; off += (size_t)CC * D;
  float* invvar = ws + off; off += D;
  float* sinv   = ws + off; off += D;
  float* q2     = ws + off; off += CC;
  float* P_T    = ws + off; off += CC * CC;
  float* init2  = ws + off; off += CC;
  float* len2   = ws + off; off += KK * CC;
  float* emhat  = ws + off; off += (size_t)B * N * CC;
  float* kmax   = ws + off; off += (size_t)B * N;

  hipLaunchKernelGGL(setup_kernel, dim3(1), dim3(256), 0, stream,
                     means, cov, tl, il, plr, wmat, invvar, sinv, q2, P_T, init2, len2, D);
  hipLaunchKernelGGL(emission_kernel, dim3((B * N) / 64), dim3(256), 0, stream,
                     feat, wmat, sinv, q2, emhat, kmax, D);
  hipLaunchKernelGGL(recur_kernel, dim3((B + 1) / 2), dim3(64), 0, stream,
                     emhat, kmax, P_T, init2, len2, lens, (float*)d_out, N, B);
}

// Round 7
// 516.885 us; speedup vs baseline: 1.7756x; 1.7756x over previous
//
#include <hip/hip_runtime.h>
#include <math.h>

#define CC 64
#define KK 20
#define DCH 32
#define LOG2E 1.4426950408889634f
#define LN2   0.6931471805599453f
#define LN2PI 1.8378770664093453f
#define BIGN  -1.0e9f

#if __has_builtin(__builtin_amdgcn_exp2f)
#define EXP2(x) __builtin_amdgcn_exp2f(x)
#else
#define EXP2(x) exp2f(x)
#endif
#if __has_builtin(__builtin_amdgcn_logf)
#define LOG2(x) __builtin_amdgcn_logf(x)
#else
#define LOG2(x) log2f(x)
#endif

typedef float v2f __attribute__((ext_vector_type(2)));
typedef float v4f __attribute__((ext_vector_type(4)));

// v_pk_fma_f32: packed 2xf32 FMA, full-rate on CDNA (the 2x fp32 path)
__device__ __forceinline__ v2f pk_fma(v2f a, v2f b, v2f c) {
  v2f d;
  asm("v_pk_fma_f32 %0, %1, %2, %3" : "=v"(d) : "v"(a), "v"(b), "v"(c));
  return d;
}

__device__ __forceinline__ float rlane(float v, int l) {
  return __int_as_float(__builtin_amdgcn_readlane(__float_as_int(v), l));
}

template <int Ctrl, int OldBits>
__device__ __forceinline__ float dpp_mov(float x) {
  return __int_as_float(__builtin_amdgcn_update_dpp(
      OldBits, __float_as_int(x), Ctrl, 0xf, 0xf, false));
}

__device__ __forceinline__ float wave_max64(float x) {
  constexpr int NI = (int)0xff800000;  // -inf
  x = fmaxf(x, dpp_mov<0x111, NI>(x));
  x = fmaxf(x, dpp_mov<0x112, NI>(x));
  x = fmaxf(x, dpp_mov<0x114, NI>(x));
  x = fmaxf(x, dpp_mov<0x118, NI>(x));
  x = fmaxf(x, dpp_mov<0x142, NI>(x));
  x = fmaxf(x, dpp_mov<0x143, NI>(x));
  return __int_as_float(__builtin_amdgcn_readlane(__float_as_int(x), 63));
}

__device__ __forceinline__ float wave_sum64(float x) {
  x += dpp_mov<0x111, 0>(x);
  x += dpp_mov<0x112, 0>(x);
  x += dpp_mov<0x114, 0>(x);
  x += dpp_mov<0x118, 0>(x);
  x += dpp_mov<0x142, 0>(x);
  x += dpp_mov<0x143, 0>(x);
  return __int_as_float(__builtin_amdgcn_readlane(__float_as_int(x), 63));
}

// ---------------------------------------------------------------------------
// Setup (unchanged)
// ---------------------------------------------------------------------------
__global__ void setup_kernel(const float* __restrict__ means,
                             const float* __restrict__ cov,
                             const float* __restrict__ tl,
                             const float* __restrict__ il,
                             const float* __restrict__ plr,
                             float* __restrict__ wmat,
                             float* __restrict__ invvar,
                             float* __restrict__ sinv,
                             float* __restrict__ q2,
                             float* __restrict__ P_T,
                             float* __restrict__ init2,
                             float* __restrict__ len2,
                             int D) {
  __shared__ float red[256];
  int tid = threadIdx.x;
  for (int d = tid; d < D; d += 256) {
    float v = 1.0f / cov[(size_t)d * D + d];
    invvar[d] = v;
    sinv[d] = sqrtf(v);
  }
  float lp_ = 0.f;
  for (int d = tid; d < D; d += 256) lp_ += logf(cov[(size_t)d * D + d]);
  red[tid] = lp_;
  __syncthreads();
  for (int s = 128; s > 0; s >>= 1) {
    if (tid < s) red[tid] += red[tid + s];
    __syncthreads();
  }
  float logdet = red[0];
  __syncthreads();
  {
    int c = tid & 63, q = tid >> 6;
    int dq = D / 4;
    float m2p = 0.f;
    for (int d = q * dq; d < (q + 1) * dq; ++d) {
      float mu = means[c * D + d];
      m2p = fmaf(mu * mu, invvar[d], m2p);
    }
    red[tid] = m2p;
  }
  __syncthreads();
  for (int i = tid; i < CC * D; i += 256) wmat[i] = means[i] * sinv[i % D];
  if (tid < CC) {
    int c = tid;
    float m2 = red[c] + red[c + 64] + red[c + 128] + red[c + 192];
    q2[c] = -0.5f * LOG2E * (m2 + logdet + (float)D * LN2PI);
    int j = c;
    float mx = -1e30f;
    for (int i2 = 0; i2 < CC; ++i2) {
      float v = (i2 == j) ? BIGN : tl[i2 * CC + j];
      mx = fmaxf(mx, v);
    }
    float s = 0.f;
    for (int i2 = 0; i2 < CC; ++i2) {
      float v = (i2 == j) ? BIGN : tl[i2 * CC + j];
      s += expf(v - mx);
    }
    float inv = 1.f / s;
    for (int i2 = 0; i2 < CC; ++i2) {
      float v = (i2 == j) ? BIGN : tl[i2 * CC + j];
      P_T[j * CC + i2] = expf(v - mx) * inv;
    }
    float mi = -1e30f;
    for (int i2 = 0; i2 < CC; ++i2) mi = fmaxf(mi, il[i2]);
    float si = 0.f;
    for (int i2 = 0; i2 < CC; ++i2) si += expf(il[i2] - mi);
    init2[c] = LOG2E * (il[c] - (mi + logf(si)));
  }
  for (int i = tid; i < KK * CC; i += 256) {
    int k = i / CC, c = i % CC;
    float lr = plr[c];
    float lp = (float)(k + 1) * lr - expf(lr) - lgammaf((float)(k + 2));
    len2[i] = LOG2E * lp;
  }
}

// ---------------------------------------------------------------------------
// Emission (unchanged)
// ---------------------------------------------------------------------------
__global__ __launch_bounds__(256) void emission_kernel(
    const float* __restrict__ feat,
    const float* __restrict__ wmat,
    const float* __restrict__ sinv,
    const float* __restrict__ q2,
    float* __restrict__ emhat,
    float* __restrict__ kmax,
    int D) {
  __shared__ __align__(16) float xsT[DCH][68];
  __shared__ __align__(16) float wsT[DCH][68];
  __shared__ float q2s[CC];
  __shared__ float x2row[64];
  __shared__ float rmx[64][17];
  __shared__ float kapsh[64];
  int tid = threadIdx.x;
  size_t row0 = (size_t)blockIdx.x * 64;
  if (tid < CC) q2s[tid] = q2[tid];
  int lr_ = tid >> 2;
  int lq  = tid & 3;
  int lj  = lq * 8;
  int tx = tid & 15, ty = tid >> 4;
  int r0 = ty * 4, c0 = tx * 4;

  const float* fx = feat + (row0 + (size_t)lr_) * D + lj;
  const float* fw = wmat + (size_t)lr_ * D + lj;
  const float* fs = sinv + lj;

  float4 xa = *(const float4*)(fx);
  float4 xb = *(const float4*)(fx + 4);
  float4 wa = *(const float4*)(fw);
  float4 wb = *(const float4*)(fw + 4);
  float4 sa = *(const float4*)(fs);
  float4 sb = *(const float4*)(fs + 4);

  float acc[4][4] = {{0.f}};
  float x2p = 0.f;

  for (int d0 = 0; d0 < D; d0 += DCH) {
    __syncthreads();
    {
      float xs0 = xa.x * sa.x, xs1 = xa.y * sa.y, xs2 = xa.z * sa.z, xs3 = xa.w * sa.w;
      float xs4 = xb.x * sb.x, xs5 = xb.y * sb.y, xs6 = xb.z * sb.z, xs7 = xb.w * sb.w;
      xsT[lj + 0][lr_] = xs0; xsT[lj + 1][lr_] = xs1;
      xsT[lj + 2][lr_] = xs2; xsT[lj + 3][lr_] = xs3;
      xsT[lj + 4][lr_] = xs4; xsT[lj + 5][lr_] = xs5;
      xsT[lj + 6][lr_] = xs6; xsT[lj + 7][lr_] = xs7;
      wsT[lj + 0][lr_] = wa.x; wsT[lj + 1][lr_] = wa.y;
      wsT[lj + 2][lr_] = wa.z; wsT[lj + 3][lr_] = wa.w;
      wsT[lj + 4][lr_] = wb.x; wsT[lj + 5][lr_] = wb.y;
      wsT[lj + 6][lr_] = wb.z; wsT[lj + 7][lr_] = wb.w;
      x2p = fmaf(xs0, xs0, x2p); x2p = fmaf(xs1, xs1, x2p);
      x2p = fmaf(xs2, xs2, x2p); x2p = fmaf(xs3, xs3, x2p);
      x2p = fmaf(xs4, xs4, x2p); x2p = fmaf(xs5, xs5, x2p);
      x2p = fmaf(xs6, xs6, x2p); x2p = fmaf(xs7, xs7, x2p);
    }
    __syncthreads();
    if (d0 + DCH < D) {
      fx += DCH; fw += DCH; fs += DCH;
      xa = *(const float4*)(fx);
      xb = *(const float4*)(fx + 4);
      wa = *(const float4*)(fw);
      wb = *(const float4*)(fw + 4);
      sa = *(const float4*)(fs);
      sb = *(const float4*)(fs + 4);
    }
    #pragma unroll
    for (int j = 0; j < DCH; ++j) {
      float4 xv = *(const float4*)&xsT[j][r0];
      float4 wv = *(const float4*)&wsT[j][c0];
      acc[0][0] = fmaf(xv.x, wv.x, acc[0][0]);
      acc[0][1] = fmaf(xv.x, wv.y, acc[0][1]);
      acc[0][2] = fmaf(xv.x, wv.z, acc[0][2]);
      acc[0][3] = fmaf(xv.x, wv.w, acc[0][3]);
      acc[1][0] = fmaf(xv.y, wv.x, acc[1][0]);
      acc[1][1] = fmaf(xv.y, wv.y, acc[1][1]);
      acc[1][2] = fmaf(xv.y, wv.z, acc[1][2]);
      acc[1][3] = fmaf(xv.y, wv.w, acc[1][3]);
      acc[2][0] = fmaf(xv.z, wv.x, acc[2][0]);
      acc[2][1] = fmaf(xv.z, wv.y, acc[2][1]);
      acc[2][2] = fmaf(xv.z, wv.z, acc[2][2]);
      acc[2][3] = fmaf(xv.z, wv.w, acc[2][3]);
      acc[3][0] = fmaf(xv.w, wv.x, acc[3][0]);
      acc[3][1] = fmaf(xv.w, wv.y, acc[3][1]);
      acc[3][2] = fmaf(xv.w, wv.z, acc[3][2]);
      acc[3][3] = fmaf(xv.w, wv.w, acc[3][3]);
    }
  }

  x2p += dpp_mov<0xB1, 0>(x2p);
  x2p += dpp_mov<0x4E, 0>(x2p);
  if (lq == 0) x2row[lr_] = x2p;
  __syncthreads();

  float e[4][4];
  #pragma unroll
  for (int i = 0; i < 4; ++i) {
    float h = 0.5f * x2row[r0 + i];
    #pragma unroll
    for (int k2 = 0; k2 < 4; ++k2)
      e[i][k2] = LOG2E * (acc[i][k2] - h) + q2s[c0 + k2];
  }
  #pragma unroll
  for (int i = 0; i < 4; ++i)
    rmx[r0 + i][tx] = fmaxf(fmaxf(e[i][0], e[i][1]), fmaxf(e[i][2], e[i][3]));
  __syncthreads();
  if (tid < 64) {
    float m = rmx[tid][0];
    #pragma unroll
    for (int j = 1; j < 16; ++j) m = fmaxf(m, rmx[tid][j]);
    kapsh[tid] = m;
    kmax[row0 + tid] = m;
  }
  __syncthreads();
  #pragma unroll
  for (int i = 0; i < 4; ++i) {
    float kp = kapsh[r0 + i];
    size_t row = row0 + r0 + i;
    float4 o;
    o.x = EXP2(e[i][0] - kp); o.y = EXP2(e[i][1] - kp);
    o.z = EXP2(e[i][2] - kp); o.w = EXP2(e[i][3] - kp);
    *(float4*)&emhat[row * CC + c0] = o;
  }
}

// ---------------------------------------------------------------------------
// Recursion v5: single wave per batch (R0-proven structure), but the matvec
// broadcast is done through LDS instead of 64 readlanes:
//   abuf[c] = a  (1 ds_write)  ->  16 uniform-address ds_read_b128 (broadcast,
//   conflict-free, same-wave DS is in-order: no barrier)  ->  a[j] in VGPRs
//   ->  32 v_pk_fma_f32 (packed fp32, full rate).
// Matvec: 128 inst -> ~56. Step total ~190 -> ~125 inst. Wall time of this
// kernel is empirically proportional to per-wave instruction count
// (R0: 190 inst -> 379ns/step; R5: 360 -> 712ns; ~2.0 ns/inst), so predicted
// step ~250-280 ns. DS latency hides under the S2/renorm/ring tail issued
// between the reads and the pk_fma consumption.
// ---------------------------------------------------------------------------
__global__ __launch_bounds__(64, 1) void recur_kernel(
    const float* __restrict__ emhat,
    const float* __restrict__ kmax,
    const float* __restrict__ P_T,
    const float* __restrict__ init2,
    const float* __restrict__ len2,
    const int* __restrict__ lengths,
    float* __restrict__ out,
    int N) {
  __shared__ __align__(16) float abuf[CC];
  int b = blockIdx.x;
  int c = threadIdx.x;

  // P as packed pairs: P2[j].{x,y} = P_T[2j][c], P_T[2j+1][c]
  v2f P2[CC / 2];
  #pragma unroll
  for (int j = 0; j < CC / 2; ++j) {
    v2f p;
    p.x = P_T[(size_t)(2 * j) * CC + c];
    p.y = P_T[(size_t)(2 * j + 1) * CC + c];
    P2[j] = p;
  }
  float W[KK + 1];
  #pragma unroll
  for (int k = 1; k <= KK; ++k) W[k] = EXP2(len2[(k - 1) * CC + c]);
  float W1 = W[1];

  const float* eh_b = emhat + (size_t)b * N * CC;
  const float* km_b = kmax + (size_t)b * N;
  int len_b = lengths[b];

  float skp = 0.f;
  for (int r = c; r < len_b; r += 64) skp += km_b[r];
  float Skap = wave_sum64(skp);

  float v = EXP2(init2[c]);
  float rho = eh_b[c];  // row 0
  float q0v = eh_b[(size_t)(1 <= N - 1 ? 1 : N - 1) * CC + c];
  float q1v = eh_b[(size_t)(2 <= N - 1 ? 2 : N - 1) * CC + c];
  float q2v = eh_b[(size_t)(3 <= N - 1 ? 3 : N - 1) * CC + c];
  float q3v = eh_b[(size_t)(4 <= N - 1 ? 4 : N - 1) * CC + c];
  float EfSum = 0.f;
  float A[KK];
  #pragma unroll
  for (int i = 0; i < KK; ++i) A[i] = 0.f;
  float rest = 0.f;

  auto body = [&](int t, float& q) {
    // ---- serial chain head ----
    float A0 = v * rho;
    float a = fmaf(A0, W1, rest);

    // ---- broadcast a through LDS (write, then uniform-address reads) ----
    abuf[c] = a;
    v2f a2[CC / 2];
    #pragma unroll
    for (int j = 0; j < CC / 4; ++j) {
      v4f t4 = *(v4f*)&abuf[4 * j];
      v2f lo, hi;
      lo.x = t4.x; lo.y = t4.y;
      hi.x = t4.z; hi.y = t4.w;
      a2[2 * j] = lo;
      a2[2 * j + 1] = hi;
    }

    if (t == len_b) {
      float s_ = wave_sum64(a);
      if (c == 0) out[b] = LN2 * (Skap + EfSum + LOG2(s_));
    }

    // ---- S2 from OLD ring (fills DS latency) ----
    float u0 = A0 * W[2], u1 = 0.f, u2 = 0.f, u3 = 0.f;
    #pragma unroll
    for (int i = 1; i + 3 <= 16; i += 4) {
      u0 = fmaf(A[i],     W[i + 2], u0);
      u1 = fmaf(A[i + 1], W[i + 3], u1);
      u2 = fmaf(A[i + 2], W[i + 4], u2);
      u3 = fmaf(A[i + 3], W[i + 5], u3);
    }
    u1 = fmaf(A[17], W[19], u1);
    u2 = fmaf(A[18], W[20], u2);
    float S2 = (u0 + u1) + (u2 + u3);

    // ---- prefetch rotation ----
    float rh = q;
    int rown = (t + 4 <= N - 1) ? (t + 4) : (N - 1);
    q = eh_b[(size_t)rown * CC + c];

    // ---- renorm (uses OLD v; fills DS latency) ----
    float vmax = wave_max64(v);
    vmax = fminf(fmaxf(vmax, 1e-20f), 1e20f);
    int eb = (__float_as_int(vmax) >> 23) & 255;
    float scale = __int_as_float((254 - eb) << 23);
    EfSum += (float)(eb - 127);
    float rhon = rh * scale;
    rest = rhon * S2;

    // ---- ring shift ----
    #pragma unroll
    for (int i = KK - 1; i >= 2; --i) A[i] = A[i - 1] * rhon;
    A[1] = A0 * rhon;

    // ---- matvec v_new = P . a : 32 packed FMAs ----
    v2f m0 = {0.f, 0.f}, m1 = {0.f, 0.f}, m2 = {0.f, 0.f}, m3 = {0.f, 0.f};
    #pragma unroll
    for (int j = 0; j < CC / 2; j += 4) {
      m0 = pk_fma(P2[j],     a2[j],     m0);
      m1 = pk_fma(P2[j + 1], a2[j + 1], m1);
      m2 = pk_fma(P2[j + 2], a2[j + 2], m2);
      m3 = pk_fma(P2[j + 3], a2[j + 3], m3);
    }
    float vnew = ((m0.x + m0.y) + (m1.x + m1.y)) +
                 ((m2.x + m2.y) + (m3.x + m3.y));

    v = vnew;
    rho = rhon;
  };

  int t = 1;
  for (; t + 3 <= N; t += 4) {
    body(t,     q0v);
    body(t + 1, q1v);
    body(t + 2, q2v);
    body(t + 3, q3v);
  }
  for (; t <= N; ++t) {
    int s = t & 3;
    if (s == 1)      body(t, q0v);
    else if (s == 2) body(t, q1v);
    else if (s == 3) body(t, q2v);
    else             body(t, q3v);
  }
}

extern "C" void kernel_launch(void* const* d_in, const int* in_sizes, int n_in,
                              void* d_out, int out_size, void* d_ws, size_t ws_size,
                              hipStream_t stream) {
  const float* feat   = (const float*)d_in[0];
  const int*   lens   = (const int*)d_in[1];
  const float* means  = (const float*)d_in[2];
  const float* cov    = (const float*)d_in[3];
  const float* tl     = (const float*)d_in[4];
  const float* il     = (const float*)d_in[5];
  const float* plr    = (const float*)d_in[6];
  int B = in_sizes[1];
  int D = in_sizes[2] / CC;
  int N = in_sizes[0] / (B * D);

  float* ws = (float*)d_ws;
  size_t off = 0;
  float* wmat   = ws + off; off += (size_t)CC * D;
  float* invvar = ws + off; off += D;
  float* sinv   = ws + off; off += D;
  float* q2     = ws + off; off += CC;
  float* P_T    = ws + off; off += CC * CC;
  float* init2  = ws + off; off += CC;
  float* len2   = ws + off; off += KK * CC;
  float* emhat  = ws + off; off += (size_t)B * N * CC;
  float* kmax   = ws + off; off += (size_t)B * N;

  hipLaunchKernelGGL(setup_kernel, dim3(1), dim3(256), 0, stream,
                     means, cov, tl, il, plr, wmat, invvar, sinv, q2, P_T, init2, len2, D);
  hipLaunchKernelGGL(emission_kernel, dim3((B * N) / 64), dim3(256), 0, stream,
                     feat, wmat, sinv, q2, emhat, kmax, D);
  hipLaunchKernelGGL(recur_kernel, dim3(B), dim3(64), 0, stream,
                     emhat, kmax, P_T, init2, len2, lens, (float*)d_out, N);
}

// Round 8
// 465.341 us; speedup vs baseline: 1.9722x; 1.1108x over previous
//
#include <hip/hip_runtime.h>
#include <math.h>

#define CC 64
#define KK 20
#define DCH 32
#define LOG2E 1.4426950408889634f
#define LN2   0.6931471805599453f
#define LN2PI 1.8378770664093453f
#define BIGN  -1.0e9f

#if __has_builtin(__builtin_amdgcn_exp2f)
#define EXP2(x) __builtin_amdgcn_exp2f(x)
#else
#define EXP2(x) exp2f(x)
#endif
#if __has_builtin(__builtin_amdgcn_logf)
#define LOG2(x) __builtin_amdgcn_logf(x)
#else
#define LOG2(x) log2f(x)
#endif

typedef float v2f __attribute__((ext_vector_type(2)));
typedef float v4f __attribute__((ext_vector_type(4)));

__device__ __forceinline__ v2f pk_fma(v2f a, v2f b, v2f c) {
  v2f d;
  asm("v_pk_fma_f32 %0, %1, %2, %3" : "=v"(d) : "v"(a), "v"(b), "v"(c));
  return d;
}

template <int Ctrl, int OldBits>
__device__ __forceinline__ float dpp_mov(float x) {
  return __int_as_float(__builtin_amdgcn_update_dpp(
      OldBits, __float_as_int(x), Ctrl, 0xf, 0xf, false));
}

__device__ __forceinline__ float wave_max64(float x) {
  constexpr int NI = (int)0xff800000;  // -inf
  x = fmaxf(x, dpp_mov<0x111, NI>(x));
  x = fmaxf(x, dpp_mov<0x112, NI>(x));
  x = fmaxf(x, dpp_mov<0x114, NI>(x));
  x = fmaxf(x, dpp_mov<0x118, NI>(x));
  x = fmaxf(x, dpp_mov<0x142, NI>(x));
  x = fmaxf(x, dpp_mov<0x143, NI>(x));
  return __int_as_float(__builtin_amdgcn_readlane(__float_as_int(x), 63));
}

__device__ __forceinline__ float wave_sum64(float x) {
  x += dpp_mov<0x111, 0>(x);
  x += dpp_mov<0x112, 0>(x);
  x += dpp_mov<0x114, 0>(x);
  x += dpp_mov<0x118, 0>(x);
  x += dpp_mov<0x142, 0>(x);
  x += dpp_mov<0x143, 0>(x);
  return __int_as_float(__builtin_amdgcn_readlane(__float_as_int(x), 63));
}

// ---------------------------------------------------------------------------
// Setup (unchanged)
// ---------------------------------------------------------------------------
__global__ void setup_kernel(const float* __restrict__ means,
                             const float* __restrict__ cov,
                             const float* __restrict__ tl,
                             const float* __restrict__ il,
                             const float* __restrict__ plr,
                             float* __restrict__ wmat,
                             float* __restrict__ invvar,
                             float* __restrict__ sinv,
                             float* __restrict__ q2,
                             float* __restrict__ P_T,
                             float* __restrict__ init2,
                             float* __restrict__ len2,
                             int D) {
  __shared__ float red[256];
  int tid = threadIdx.x;
  for (int d = tid; d < D; d += 256) {
    float v = 1.0f / cov[(size_t)d * D + d];
    invvar[d] = v;
    sinv[d] = sqrtf(v);
  }
  float lp_ = 0.f;
  for (int d = tid; d < D; d += 256) lp_ += logf(cov[(size_t)d * D + d]);
  red[tid] = lp_;
  __syncthreads();
  for (int s = 128; s > 0; s >>= 1) {
    if (tid < s) red[tid] += red[tid + s];
    __syncthreads();
  }
  float logdet = red[0];
  __syncthreads();
  {
    int c = tid & 63, q = tid >> 6;
    int dq = D / 4;
    float m2p = 0.f;
    for (int d = q * dq; d < (q + 1) * dq; ++d) {
      float mu = means[c * D + d];
      m2p = fmaf(mu * mu, invvar[d], m2p);
    }
    red[tid] = m2p;
  }
  __syncthreads();
  for (int i = tid; i < CC * D; i += 256) wmat[i] = means[i] * sinv[i % D];
  if (tid < CC) {
    int c = tid;
    float m2 = red[c] + red[c + 64] + red[c + 128] + red[c + 192];
    q2[c] = -0.5f * LOG2E * (m2 + logdet + (float)D * LN2PI);
    int j = c;
    float mx = -1e30f;
    for (int i2 = 0; i2 < CC; ++i2) {
      float v = (i2 == j) ? BIGN : tl[i2 * CC + j];
      mx = fmaxf(mx, v);
    }
    float s = 0.f;
    for (int i2 = 0; i2 < CC; ++i2) {
      float v = (i2 == j) ? BIGN : tl[i2 * CC + j];
      s += expf(v - mx);
    }
    float inv = 1.f / s;
    for (int i2 = 0; i2 < CC; ++i2) {
      float v = (i2 == j) ? BIGN : tl[i2 * CC + j];
      P_T[j * CC + i2] = expf(v - mx) * inv;
    }
    float mi = -1e30f;
    for (int i2 = 0; i2 < CC; ++i2) mi = fmaxf(mi, il[i2]);
    float si = 0.f;
    for (int i2 = 0; i2 < CC; ++i2) si += expf(il[i2] - mi);
    init2[c] = LOG2E * (il[c] - (mi + logf(si)));
  }
  for (int i = tid; i < KK * CC; i += 256) {
    int k = i / CC, c = i % CC;
    float lr = plr[c];
    float lp = (float)(k + 1) * lr - expf(lr) - lgammaf((float)(k + 2));
    len2[i] = LOG2E * lp;
  }
}

// ---------------------------------------------------------------------------
// Emission (unchanged)
// ---------------------------------------------------------------------------
__global__ __launch_bounds__(256) void emission_kernel(
    const float* __restrict__ feat,
    const float* __restrict__ wmat,
    const float* __restrict__ sinv,
    const float* __restrict__ q2,
    float* __restrict__ emhat,
    float* __restrict__ kmax,
    int D) {
  __shared__ __align__(16) float xsT[DCH][68];
  __shared__ __align__(16) float wsT[DCH][68];
  __shared__ float q2s[CC];
  __shared__ float x2row[64];
  __shared__ float rmx[64][17];
  __shared__ float kapsh[64];
  int tid = threadIdx.x;
  size_t row0 = (size_t)blockIdx.x * 64;
  if (tid < CC) q2s[tid] = q2[tid];
  int lr_ = tid >> 2;
  int lq  = tid & 3;
  int lj  = lq * 8;
  int tx = tid & 15, ty = tid >> 4;
  int r0 = ty * 4, c0 = tx * 4;

  const float* fx = feat + (row0 + (size_t)lr_) * D + lj;
  const float* fw = wmat + (size_t)lr_ * D + lj;
  const float* fs = sinv + lj;

  float4 xa = *(const float4*)(fx);
  float4 xb = *(const float4*)(fx + 4);
  float4 wa = *(const float4*)(fw);
  float4 wb = *(const float4*)(fw + 4);
  float4 sa = *(const float4*)(fs);
  float4 sb = *(const float4*)(fs + 4);

  float acc[4][4] = {{0.f}};
  float x2p = 0.f;

  for (int d0 = 0; d0 < D; d0 += DCH) {
    __syncthreads();
    {
      float xs0 = xa.x * sa.x, xs1 = xa.y * sa.y, xs2 = xa.z * sa.z, xs3 = xa.w * sa.w;
      float xs4 = xb.x * sb.x, xs5 = xb.y * sb.y, xs6 = xb.z * sb.z, xs7 = xb.w * sb.w;
      xsT[lj + 0][lr_] = xs0; xsT[lj + 1][lr_] = xs1;
      xsT[lj + 2][lr_] = xs2; xsT[lj + 3][lr_] = xs3;
      xsT[lj + 4][lr_] = xs4; xsT[lj + 5][lr_] = xs5;
      xsT[lj + 6][lr_] = xs6; xsT[lj + 7][lr_] = xs7;
      wsT[lj + 0][lr_] = wa.x; wsT[lj + 1][lr_] = wa.y;
      wsT[lj + 2][lr_] = wa.z; wsT[lj + 3][lr_] = wa.w;
      wsT[lj + 4][lr_] = wb.x; wsT[lj + 5][lr_] = wb.y;
      wsT[lj + 6][lr_] = wb.z; wsT[lj + 7][lr_] = wb.w;
      x2p = fmaf(xs0, xs0, x2p); x2p = fmaf(xs1, xs1, x2p);
      x2p = fmaf(xs2, xs2, x2p); x2p = fmaf(xs3, xs3, x2p);
      x2p = fmaf(xs4, xs4, x2p); x2p = fmaf(xs5, xs5, x2p);
      x2p = fmaf(xs6, xs6, x2p); x2p = fmaf(xs7, xs7, x2p);
    }
    __syncthreads();
    if (d0 + DCH < D) {
      fx += DCH; fw += DCH; fs += DCH;
      xa = *(const float4*)(fx);
      xb = *(const float4*)(fx + 4);
      wa = *(const float4*)(fw);
      wb = *(const float4*)(fw + 4);
      sa = *(const float4*)(fs);
      sb = *(const float4*)(fs + 4);
    }
    #pragma unroll
    for (int j = 0; j < DCH; ++j) {
      float4 xv = *(const float4*)&xsT[j][r0];
      float4 wv = *(const float4*)&wsT[j][c0];
      acc[0][0] = fmaf(xv.x, wv.x, acc[0][0]);
      acc[0][1] = fmaf(xv.x, wv.y, acc[0][1]);
      acc[0][2] = fmaf(xv.x, wv.z, acc[0][2]);
      acc[0][3] = fmaf(xv.x, wv.w, acc[0][3]);
      acc[1][0] = fmaf(xv.y, wv.x, acc[1][0]);
      acc[1][1] = fmaf(xv.y, wv.y, acc[1][1]);
      acc[1][2] = fmaf(xv.y, wv.z, acc[1][2]);
      acc[1][3] = fmaf(xv.y, wv.w, acc[1][3]);
      acc[2][0] = fmaf(xv.z, wv.x, acc[2][0]);
      acc[2][1] = fmaf(xv.z, wv.y, acc[2][1]);
      acc[2][2] = fmaf(xv.z, wv.z, acc[2][2]);
      acc[2][3] = fmaf(xv.z, wv.w, acc[2][3]);
      acc[3][0] = fmaf(xv.w, wv.x, acc[3][0]);
      acc[3][1] = fmaf(xv.w, wv.y, acc[3][1]);
      acc[3][2] = fmaf(xv.w, wv.z, acc[3][2]);
      acc[3][3] = fmaf(xv.w, wv.w, acc[3][3]);
    }
  }

  x2p += dpp_mov<0xB1, 0>(x2p);
  x2p += dpp_mov<0x4E, 0>(x2p);
  if (lq == 0) x2row[lr_] = x2p;
  __syncthreads();

  float e[4][4];
  #pragma unroll
  for (int i = 0; i < 4; ++i) {
    float h = 0.5f * x2row[r0 + i];
    #pragma unroll
    for (int k2 = 0; k2 < 4; ++k2)
      e[i][k2] = LOG2E * (acc[i][k2] - h) + q2s[c0 + k2];
  }
  #pragma unroll
  for (int i = 0; i < 4; ++i)
    rmx[r0 + i][tx] = fmaxf(fmaxf(e[i][0], e[i][1]), fmaxf(e[i][2], e[i][3]));
  __syncthreads();
  if (tid < 64) {
    float m = rmx[tid][0];
    #pragma unroll
    for (int j = 1; j < 16; ++j) m = fmaxf(m, rmx[tid][j]);
    kapsh[tid] = m;
    kmax[row0 + tid] = m;
  }
  __syncthreads();
  #pragma unroll
  for (int i = 0; i < 4; ++i) {
    float kp = kapsh[r0 + i];
    size_t row = row0 + r0 + i;
    float4 o;
    o.x = EXP2(e[i][0] - kp); o.y = EXP2(e[i][1] - kp);
    o.z = EXP2(e[i][2] - kp); o.w = EXP2(e[i][3] - kp);
    *(float4*)&emhat[row * CC + c0] = o;
  }
}

// ---------------------------------------------------------------------------
// Recursion v6: v5 (LDS-broadcast matvec, 332us) + TWO-STEP FUSION of the
// linear tail. Per pair (t, t+1):
//   D1 = sum_{1..18} A[i]W[i+2];  D2 = sum_{1..17} A[i]W[i+3]   (old ring)
//   S2_a = A0a*W2 + D1;           rest_a = rhon_a*S2_a
//   S2_b = A0b*W2 + rhon_a*(A0a*W3 + D2);  rest_b = rhon_b*S2_b  (exact)
//   ring shifts ONCE by 2: A[i] = A[i-2]*(rhon_a*rhon_b)  (19 ops vs 38)
//   renorm ONCE per pair (scale folded into rhon_a; EfSum exact; drift
//   between renorms is a few bits -> fp32-safe)
// ~103 inst/step vs ~166 measured-equivalent. Empirical law: 2ns/inst.
// ---------------------------------------------------------------------------
__global__ __launch_bounds__(64, 1) void recur_kernel(
    const float* __restrict__ emhat,
    const float* __restrict__ kmax,
    const float* __restrict__ P_T,
    const float* __restrict__ init2,
    const float* __restrict__ len2,
    const int* __restrict__ lengths,
    float* __restrict__ out,
    int N) {
  __shared__ __align__(16) float abuf[CC];
  int b = blockIdx.x;
  int c = threadIdx.x;

  v2f P2[CC / 2];
  #pragma unroll
  for (int j = 0; j < CC / 2; ++j) {
    v2f p;
    p.x = P_T[(size_t)(2 * j) * CC + c];
    p.y = P_T[(size_t)(2 * j + 1) * CC + c];
    P2[j] = p;
  }
  float W[KK + 1];
  #pragma unroll
  for (int k = 1; k <= KK; ++k) W[k] = EXP2(len2[(k - 1) * CC + c]);
  float W1 = W[1];

  const float* eh_b = emhat + (size_t)b * N * CC;
  const float* km_b = kmax + (size_t)b * N;
  int len_b = lengths[b];

  float skp = 0.f;
  for (int r = c; r < len_b; r += 64) skp += km_b[r];
  float Skap = wave_sum64(skp);

  float v = EXP2(init2[c]);
  float rho = eh_b[c];  // row 0
  float q0v = eh_b[(size_t)(1 <= N - 1 ? 1 : N - 1) * CC + c];
  float q1v = eh_b[(size_t)(2 <= N - 1 ? 2 : N - 1) * CC + c];
  float q2v = eh_b[(size_t)(3 <= N - 1 ? 3 : N - 1) * CC + c];
  float q3v = eh_b[(size_t)(4 <= N - 1 ? 4 : N - 1) * CC + c];
  float EfSum = 0.f;
  float A[KK];
  #pragma unroll
  for (int i = 0; i < KK; ++i) A[i] = 0.f;
  float rest = 0.f;

  // LDS broadcast + packed matvec (shared by both bodies)
  auto matvec = [&](float a) -> float {
    abuf[c] = a;
    v2f a2[CC / 2];
    #pragma unroll
    for (int j = 0; j < CC / 4; ++j) {
      v4f t4 = *(v4f*)&abuf[4 * j];
      v2f lo, hi;
      lo.x = t4.x; lo.y = t4.y;
      hi.x = t4.z; hi.y = t4.w;
      a2[2 * j] = lo;
      a2[2 * j + 1] = hi;
    }
    v2f m0 = {0.f, 0.f}, m1 = {0.f, 0.f}, m2 = {0.f, 0.f}, m3 = {0.f, 0.f};
    #pragma unroll
    for (int j = 0; j < CC / 2; j += 4) {
      m0 = pk_fma(P2[j],     a2[j],     m0);
      m1 = pk_fma(P2[j + 1], a2[j + 1], m1);
      m2 = pk_fma(P2[j + 2], a2[j + 2], m2);
      m3 = pk_fma(P2[j + 3], a2[j + 3], m3);
    }
    return ((m0.x + m0.y) + (m1.x + m1.y)) + ((m2.x + m2.y) + (m3.x + m3.y));
  };

  // ---- fused pair body: steps t (renorm) and t+1 (no renorm) ----
  auto body2 = [&](int t, float& qA, float& qB) {
    // ===== sub-step a (t) =====
    float A0a = v * rho;
    float aa = fmaf(A0a, W1, rest);

    // start broadcast early; D1 + renorm fill the DS shadow
    abuf[c] = aa;
    v2f a2[CC / 2];
    #pragma unroll
    for (int j = 0; j < CC / 4; ++j) {
      v4f t4 = *(v4f*)&abuf[4 * j];
      v2f lo, hi;
      lo.x = t4.x; lo.y = t4.y;
      hi.x = t4.z; hi.y = t4.w;
      a2[2 * j] = lo;
      a2[2 * j + 1] = hi;
    }

    if (t == len_b) {
      float s_ = wave_sum64(aa);
      if (c == 0) out[b] = LN2 * (Skap + EfSum + LOG2(s_));
    }

    // D1 = sum_{i=1..18} A[i]*W[i+2]
    float d10 = 0.f, d11 = 0.f, d12 = 0.f, d13 = 0.f;
    #pragma unroll
    for (int i = 1; i + 3 <= 16; i += 4) {
      d10 = fmaf(A[i],     W[i + 2], d10);
      d11 = fmaf(A[i + 1], W[i + 3], d11);
      d12 = fmaf(A[i + 2], W[i + 4], d12);
      d13 = fmaf(A[i + 3], W[i + 5], d13);
    }
    d10 = fmaf(A[17], W[19], d10);
    d11 = fmaf(A[18], W[20], d11);
    float D1 = (d10 + d11) + (d12 + d13);

    // renorm (once per pair; uses current v)
    float vmax = wave_max64(v);
    vmax = fminf(fmaxf(vmax, 1e-20f), 1e20f);
    int eb = (__float_as_int(vmax) >> 23) & 255;
    float scale = __int_as_float((254 - eb) << 23);
    EfSum += (float)(eb - 127);

    float rha = qA;
    int rowa = (t + 4 <= N - 1) ? (t + 4) : (N - 1);
    qA = eh_b[(size_t)rowa * CC + c];
    float rhon_a = rha * scale;

    float S2a = fmaf(A0a, W[2], D1);
    rest = rhon_a * S2a;

    // matvec consume (reads were issued above)
    {
      v2f m0 = {0.f, 0.f}, m1 = {0.f, 0.f}, m2 = {0.f, 0.f}, m3 = {0.f, 0.f};
      #pragma unroll
      for (int j = 0; j < CC / 2; j += 4) {
        m0 = pk_fma(P2[j],     a2[j],     m0);
        m1 = pk_fma(P2[j + 1], a2[j + 1], m1);
        m2 = pk_fma(P2[j + 2], a2[j + 2], m2);
        m3 = pk_fma(P2[j + 3], a2[j + 3], m3);
      }
      v = ((m0.x + m0.y) + (m1.x + m1.y)) + ((m2.x + m2.y) + (m3.x + m3.y));
    }

    // ===== sub-step b (t+1) =====
    float A0b = v * rhon_a;
    float ab = fmaf(A0b, W1, rest);

    abuf[c] = ab;
    v2f b2[CC / 2];
    #pragma unroll
    for (int j = 0; j < CC / 4; ++j) {
      v4f t4 = *(v4f*)&abuf[4 * j];
      v2f lo, hi;
      lo.x = t4.x; lo.y = t4.y;
      hi.x = t4.z; hi.y = t4.w;
      b2[2 * j] = lo;
      b2[2 * j + 1] = hi;
    }

    if (t + 1 == len_b) {
      float s_ = wave_sum64(ab);
      if (c == 0) out[b] = LN2 * (Skap + EfSum + LOG2(s_));
    }

    // D2 = sum_{i=1..17} A[i]*W[i+3]  (OLD ring; fills DS shadow)
    float d20 = 0.f, d21 = 0.f, d22 = 0.f, d23 = 0.f;
    #pragma unroll
    for (int i = 1; i + 3 <= 16; i += 4) {
      d20 = fmaf(A[i],     W[i + 3], d20);
      d21 = fmaf(A[i + 1], W[i + 4], d21);
      d22 = fmaf(A[i + 2], W[i + 5], d22);
      d23 = fmaf(A[i + 3], W[i + 6], d23);
    }
    d20 = fmaf(A[17], W[20], d20);
    float D2 = (d20 + d21) + (d22 + d23);

    float rhb = qB;
    int rowb = (t + 5 <= N - 1) ? (t + 5) : (N - 1);
    qB = eh_b[(size_t)rowb * CC + c];
    float rhon_b = rhb;  // no renorm this sub-step

    float S2b = fmaf(A0b, W[2], rhon_a * fmaf(A0a, W[3], D2));
    rest = rhon_b * S2b;

    // ring double-shift: A[i] = A[i-2]*(rhon_a*rhon_b)
    float r2 = rhon_a * rhon_b;
    #pragma unroll
    for (int i = 18; i >= 3; --i) A[i] = A[i - 2] * r2;
    A[2] = A0a * r2;
    A[1] = A0b * rhon_b;

    // matvec consume
    {
      v2f m0 = {0.f, 0.f}, m1 = {0.f, 0.f}, m2 = {0.f, 0.f}, m3 = {0.f, 0.f};
      #pragma unroll
      for (int j = 0; j < CC / 2; j += 4) {
        m0 = pk_fma(P2[j],     b2[j],     m0);
        m1 = pk_fma(P2[j + 1], b2[j + 1], m1);
        m2 = pk_fma(P2[j + 2], b2[j + 2], m2);
        m3 = pk_fma(P2[j + 3], b2[j + 3], m3);
      }
      v = ((m0.x + m0.y) + (m1.x + m1.y)) + ((m2.x + m2.y) + (m3.x + m3.y));
    }

    rho = rhon_b;
  };

  // single-step fallback body (tail; per-step renorm — exact)
  auto body1 = [&](int t, float& q) {
    float A0 = v * rho;
    float a = fmaf(A0, W1, rest);
    float vn = matvec(a);
    if (t == len_b) {
      float s_ = wave_sum64(a);
      if (c == 0) out[b] = LN2 * (Skap + EfSum + LOG2(s_));
    }
    float d10 = A0 * W[2], d11 = 0.f, d12 = 0.f, d13 = 0.f;
    #pragma unroll
    for (int i = 1; i + 3 <= 16; i += 4) {
      d10 = fmaf(A[i],     W[i + 2], d10);
      d11 = fmaf(A[i + 1], W[i + 3], d11);
      d12 = fmaf(A[i + 2], W[i + 4], d12);
      d13 = fmaf(A[i + 3], W[i + 5], d13);
    }
    d11 = fmaf(A[17], W[19], d11);
    d12 = fmaf(A[18], W[20], d12);
    float S2 = (d10 + d11) + (d12 + d13);
    float rh = q;
    int rown = (t + 4 <= N - 1) ? (t + 4) : (N - 1);
    q = eh_b[(size_t)rown * CC + c];
    float vmax = wave_max64(v);
    vmax = fminf(fmaxf(vmax, 1e-20f), 1e20f);
    int eb = (__float_as_int(vmax) >> 23) & 255;
    float scale = __int_as_float((254 - eb) << 23);
    EfSum += (float)(eb - 127);
    float rhon = rh * scale;
    rest = rhon * S2;
    #pragma unroll
    for (int i = 18; i >= 2; --i) A[i] = A[i - 1] * rhon;
    A[1] = A0 * rhon;
    v = vn;
    rho = rhon;
  };

  int t = 1;
  for (; t + 3 <= N; t += 4) {
    body2(t,     q0v, q1v);
    body2(t + 2, q2v, q3v);
  }
  for (; t <= N; ++t) {
    int s = t & 3;
    if (s == 1)      body1(t, q0v);
    else if (s == 2) body1(t, q1v);
    else if (s == 3) body1(t, q2v);
    else             body1(t, q3v);
  }
}

extern "C" void kernel_launch(void* const* d_in, const int* in_sizes, int n_in,
                              void* d_out, int out_size, void* d_ws, size_t ws_size,
                              hipStream_t stream) {
  const float* feat   = (const float*)d_in[0];
  const int*   lens   = (const int*)d_in[1];
  const float* means  = (const float*)d_in[2];
  const float* cov    = (const float*)d_in[3];
  const float* tl     = (const float*)d_in[4];
  const float* il     = (const float*)d_in[5];
  const float* plr    = (const float*)d_in[6];
  int B = in_sizes[1];
  int D = in_sizes[2] / CC;
  int N = in_sizes[0] / (B * D);

  float* ws = (float*)d_ws;
  size_t off = 0;
  float* wmat   = ws + off; off += (size_t)CC * D;
  float* invvar = ws + off; off += D;
  float* sinv   = ws + off; off += D;
  float* q2     = ws + off; off += CC;
  float* P_T    = ws + off; off += CC * CC;
  float* init2  = ws + off; off += CC;
  float* len2   = ws + off; off += KK * CC;
  float* emhat  = ws + off; off += (size_t)B * N * CC;
  float* kmax   = ws + off; off += (size_t)B * N;

  hipLaunchKernelGGL(setup_kernel, dim3(1), dim3(256), 0, stream,
                     means, cov, tl, il, plr, wmat, invvar, sinv, q2, P_T, init2, len2, D);
  hipLaunchKernelGGL(emission_kernel, dim3((B * N) / 64), dim3(256), 0, stream,
                     feat, wmat, sinv, q2, emhat, kmax, D);
  hipLaunchKernelGGL(recur_kernel, dim3(B), dim3(64), 0, stream,
                     emhat, kmax, P_T, init2, len2, lens, (float*)d_out, N);
}